// Round 1
// baseline (911.255 us; speedup 1.0000x reference)
//
#include <hip/hip_runtime.h>
#include <hip/hip_bf16.h>
#include <math.h>

#define N_NODES 20000
#define N_EDGES 320000
#define N_GRAPHS 64

// ---------------------------------------------------------------- CSR build
__global__ void hist_k(const int* __restrict__ dst, int* __restrict__ deg, int E) {
    int e = blockIdx.x * 256 + threadIdx.x;
    if (e < E) atomicAdd(&deg[dst[e]], 1);
}

__global__ void scan_k(const int* __restrict__ deg, int* __restrict__ offs,
                       int* __restrict__ cursor, int n) {
    __shared__ int buf[1024];
    __shared__ int s_carry;
    int tid = threadIdx.x;
    if (tid == 0) s_carry = 0;
    __syncthreads();
    for (int base = 0; base < n; base += 1024) {
        int carry = s_carry;
        int i = base + tid;
        int v = (i < n) ? deg[i] : 0;
        buf[tid] = v;
        __syncthreads();
        for (int off = 1; off < 1024; off <<= 1) {
            int t = (tid >= off) ? buf[tid - off] : 0;
            __syncthreads();
            buf[tid] += t;
            __syncthreads();
        }
        int incl = buf[tid];
        if (i < n) { int ex = carry + incl - v; offs[i] = ex; cursor[i] = ex; }
        if (tid == 1023) s_carry = carry + incl;
        __syncthreads();
    }
    if (tid == 0) offs[n] = s_carry;
}

__global__ void scatter_k(const int* __restrict__ src, const int* __restrict__ dst,
                          int* __restrict__ cursor, int* __restrict__ csr_src,
                          int* __restrict__ csr_eid, int E) {
    int e = blockIdx.x * 256 + threadIdx.x;
    if (e < E) {
        int d = dst[e];
        int p = atomicAdd(&cursor[d], 1);
        csr_src[p] = src[e];
        csr_eid[p] = e;
    }
}

// ---------------------------------------------------------------- fp32 GEMM
// C[M,N] = A[M,K] @ B[K,N] (+bias). 64x64 tile, 256 threads, 4x4 microtile.
__global__ __launch_bounds__(256) void gemm_k(const float* __restrict__ A,
                                              const float* __restrict__ B,
                                              float* __restrict__ C,
                                              const float* __restrict__ bias,
                                              int M, int N, int K) {
    __shared__ float As[16][65];
    __shared__ float Bs[16][64];
    int tid = threadIdx.x;
    int tx = tid & 15, ty = tid >> 4;
    int row0 = blockIdx.y * 64, col0 = blockIdx.x * 64;
    float acc[4][4] = {};
    for (int k0 = 0; k0 < K; k0 += 16) {
        #pragma unroll
        for (int i = 0; i < 4; ++i) {
            int idx = tid + i * 256;
            int m = idx >> 4, kk = idx & 15;
            int gm = row0 + m, gk = k0 + kk;
            As[kk][m] = (gm < M && gk < K) ? A[(size_t)gm * K + gk] : 0.f;
        }
        #pragma unroll
        for (int i = 0; i < 4; ++i) {
            int idx = tid + i * 256;
            int kk = idx >> 6, n = idx & 63;
            int gk = k0 + kk, gn = col0 + n;
            Bs[kk][n] = (gk < K && gn < N) ? B[(size_t)gk * N + gn] : 0.f;
        }
        __syncthreads();
        #pragma unroll
        for (int kk = 0; kk < 16; ++kk) {
            float a[4], b[4];
            #pragma unroll
            for (int i = 0; i < 4; ++i) a[i] = As[kk][ty * 4 + i];
            #pragma unroll
            for (int j = 0; j < 4; ++j) b[j] = Bs[kk][tx * 4 + j];
            #pragma unroll
            for (int i = 0; i < 4; ++i)
                #pragma unroll
                for (int j = 0; j < 4; ++j) acc[i][j] += a[i] * b[j];
        }
        __syncthreads();
    }
    #pragma unroll
    for (int i = 0; i < 4; ++i) {
        int gm = row0 + ty * 4 + i;
        if (gm >= M) continue;
        #pragma unroll
        for (int j = 0; j < 4; ++j) {
            int gn = col0 + tx * 4 + j;
            if (gn < N) C[(size_t)gm * N + gn] = acc[i][j] + (bias ? bias[gn] : 0.f);
        }
    }
}

// ------------------------------------------------- attention scores as/ad
// as[n,h] = sum_c h[n,h*C+c]*a_src[h*C+c];  ad likewise. One wave per node.
__global__ void attn_k(const float* __restrict__ h, const float* __restrict__ a_s,
                       const float* __restrict__ a_d, float* __restrict__ as_,
                       float* __restrict__ ad_, int H, int C) {
    int j = blockIdx.x;
    int lane = threadIdx.x;  // 64
    const float* row = h + (size_t)j * H * C;
    for (int hh = 0; hh < H; ++hh) {
        float ss = 0.f, dd = 0.f;
        for (int c = lane; c < C; c += 64) {
            float v = row[hh * C + c];
            ss += v * a_s[hh * C + c];
            dd += v * a_d[hh * C + c];
        }
        #pragma unroll
        for (int off = 32; off; off >>= 1) {
            ss += __shfl_xor(ss, off);
            dd += __shfl_xor(dd, off);
        }
        if (lane == 0) { as_[j * H + hh] = ss; ad_[j * H + hh] = dd; }
    }
}

__device__ __forceinline__ float leaky02(float v) { return v > 0.f ? v : 0.2f * v; }

// ------------------------------------------- aggregation, concat (H=4,C=64)
// xout[j,t] = relu( sum_e alpha[e,h]*h[src,t] + bgat[t] + lin[j,t] ), t = h*64+c
__global__ __launch_bounds__(256) void agg_concat_k(
    const float* __restrict__ h, const float* __restrict__ as_,
    const float* __restrict__ ad_, const int* __restrict__ offs,
    const int* __restrict__ csr_src, const float* __restrict__ lin,
    const float* __restrict__ bgat, float* __restrict__ xout) {
    int j = blockIdx.x;
    int tid = threadIdx.x;  // 256
    int o0 = offs[j], deg = offs[j + 1] - o0;
    __shared__ float s_m[4], s_d[4], s_adj[4];
    __shared__ float s_alpha[64 * 4];
    __shared__ int s_src[64];
    if (tid < 4) s_adj[tid] = ad_[j * 4 + tid];
    __syncthreads();
    if (tid < 64) {
        float mx[4] = {-3.4e38f, -3.4e38f, -3.4e38f, -3.4e38f};
        for (int e = tid; e < deg; e += 64) {
            int s = csr_src[o0 + e];
            #pragma unroll
            for (int hh = 0; hh < 4; ++hh) {
                float v = leaky02(as_[s * 4 + hh] + s_adj[hh]);
                mx[hh] = fmaxf(mx[hh], v);
            }
        }
        #pragma unroll
        for (int off = 32; off; off >>= 1)
            #pragma unroll
            for (int hh = 0; hh < 4; ++hh) mx[hh] = fmaxf(mx[hh], __shfl_xor(mx[hh], off));
        float sm[4] = {0.f, 0.f, 0.f, 0.f};
        for (int e = tid; e < deg; e += 64) {
            int s = csr_src[o0 + e];
            #pragma unroll
            for (int hh = 0; hh < 4; ++hh) {
                float v = leaky02(as_[s * 4 + hh] + s_adj[hh]);
                sm[hh] += __expf(v - mx[hh]);
            }
        }
        #pragma unroll
        for (int off = 32; off; off >>= 1)
            #pragma unroll
            for (int hh = 0; hh < 4; ++hh) sm[hh] += __shfl_xor(sm[hh], off);
        if (tid == 0) {
            #pragma unroll
            for (int hh = 0; hh < 4; ++hh) { s_m[hh] = mx[hh]; s_d[hh] = sm[hh]; }
        }
    }
    __syncthreads();
    int myh = tid >> 6;
    float acc = 0.f;
    for (int e0 = 0; e0 < deg; e0 += 64) {
        int ne = min(64, deg - e0);
        {
            int e_l = tid >> 2, ah = tid & 3;
            if (e_l < ne) {
                int s = csr_src[o0 + e0 + e_l];
                if (ah == 0) s_src[e_l] = s;
                float v = leaky02(as_[s * 4 + ah] + s_adj[ah]);
                s_alpha[e_l * 4 + ah] = __expf(v - s_m[ah]) / (s_d[ah] + 1e-16f);
            }
        }
        __syncthreads();
        for (int e_l = 0; e_l < ne; ++e_l) {
            int s = s_src[e_l];
            acc += s_alpha[e_l * 4 + myh] * h[(size_t)s * 256 + tid];
        }
        __syncthreads();
    }
    xout[(size_t)j * 256 + tid] = fmaxf(acc + bgat[tid] + lin[(size_t)j * 256 + tid], 0.f);
}

// --------------------------------------- aggregation, mean (H=6,C=128) + att
// y[j,c] = relu( (1/6) sum_h sum_e alpha*h[src,h*128+c] + bgat[c] + xres[j,c] )
// att[eid,h] = alpha
__global__ __launch_bounds__(256) void agg_mean_k(
    const float* __restrict__ h, const float* __restrict__ as_,
    const float* __restrict__ ad_, const int* __restrict__ offs,
    const int* __restrict__ csr_src, const int* __restrict__ csr_eid,
    const float* __restrict__ xres, const float* __restrict__ bgat,
    float* __restrict__ y, float* __restrict__ att) {
    int j = blockIdx.x;
    int tid = threadIdx.x;  // 256
    int o0 = offs[j], deg = offs[j + 1] - o0;
    __shared__ float s_m[6], s_d[6], s_adj[6];
    __shared__ float s_alpha[32 * 6];
    __shared__ int s_src[32];
    if (tid < 6) s_adj[tid] = ad_[j * 6 + tid];
    __syncthreads();
    if (tid < 64) {
        float mx[6], sm[6];
        #pragma unroll
        for (int hh = 0; hh < 6; ++hh) { mx[hh] = -3.4e38f; sm[hh] = 0.f; }
        for (int e = tid; e < deg; e += 64) {
            int s = csr_src[o0 + e];
            #pragma unroll
            for (int hh = 0; hh < 6; ++hh) {
                float v = leaky02(as_[s * 6 + hh] + s_adj[hh]);
                mx[hh] = fmaxf(mx[hh], v);
            }
        }
        #pragma unroll
        for (int off = 32; off; off >>= 1)
            #pragma unroll
            for (int hh = 0; hh < 6; ++hh) mx[hh] = fmaxf(mx[hh], __shfl_xor(mx[hh], off));
        for (int e = tid; e < deg; e += 64) {
            int s = csr_src[o0 + e];
            #pragma unroll
            for (int hh = 0; hh < 6; ++hh) {
                float v = leaky02(as_[s * 6 + hh] + s_adj[hh]);
                sm[hh] += __expf(v - mx[hh]);
            }
        }
        #pragma unroll
        for (int off = 32; off; off >>= 1)
            #pragma unroll
            for (int hh = 0; hh < 6; ++hh) sm[hh] += __shfl_xor(sm[hh], off);
        if (tid == 0) {
            #pragma unroll
            for (int hh = 0; hh < 6; ++hh) { s_m[hh] = mx[hh]; s_d[hh] = sm[hh]; }
        }
    }
    __syncthreads();
    float acc = 0.f;
    for (int e0 = 0; e0 < deg; e0 += 32) {
        int ne = min(32, deg - e0);
        if (tid < 192) {
            int e_l = tid / 6, ah = tid - e_l * 6;
            if (e_l < ne) {
                int p = o0 + e0 + e_l;
                int s = csr_src[p];
                if (ah == 0) s_src[e_l] = s;
                float v = leaky02(as_[s * 6 + ah] + s_adj[ah]);
                float al = __expf(v - s_m[ah]) / (s_d[ah] + 1e-16f);
                s_alpha[e_l * 6 + ah] = al;
                att[(size_t)csr_eid[p] * 6 + ah] = al;
            }
        }
        __syncthreads();
        if (tid < 128) {
            for (int e_l = 0; e_l < ne; ++e_l) {
                int s = s_src[e_l];
                const float* hr = h + (size_t)s * 768 + tid;
                #pragma unroll
                for (int hh = 0; hh < 6; ++hh) acc += s_alpha[e_l * 6 + hh] * hr[hh * 128];
            }
        }
        __syncthreads();
    }
    if (tid < 128)
        y[(size_t)j * 128 + tid] =
            fmaxf(acc * (1.f / 6.f) + bgat[tid] + xres[(size_t)j * 128 + tid], 0.f);
}

// ---------------------------------------------------------------- BatchNorm
__global__ void bn_pass1_k(const float* __restrict__ y, float* __restrict__ sums, int N) {
    int c = threadIdx.x;  // 128
    float s = 0.f;
    for (int r = blockIdx.x; r < N; r += gridDim.x) s += y[(size_t)r * 128 + c];
    atomicAdd(&sums[c], s);
}
__global__ void bn_mu_k(const float* __restrict__ sums, float* __restrict__ mu, int N) {
    int c = threadIdx.x;
    mu[c] = sums[c] / (float)N;
}
__global__ void bn_pass2_k(const float* __restrict__ y, const float* __restrict__ mu,
                           float* __restrict__ sums, int N) {
    int c = threadIdx.x;
    float m = mu[c], s = 0.f;
    for (int r = blockIdx.x; r < N; r += gridDim.x) {
        float d = y[(size_t)r * 128 + c] - m;
        s += d * d;
    }
    atomicAdd(&sums[c], s);
}
__global__ void bn_scale_k(const float* __restrict__ sums, const float* __restrict__ mu,
                           const float* __restrict__ gamma, const float* __restrict__ beta,
                           float* __restrict__ scale, float* __restrict__ shift, int N) {
    int c = threadIdx.x;
    float var = sums[c] / (float)N;
    float inv = 1.0f / sqrtf(var + 1e-5f);
    float sc = inv * gamma[c];
    scale[c] = sc;
    shift[c] = beta[c] - mu[c] * sc;
}

// ---------------------------------------------------------------- max pool
__device__ __forceinline__ unsigned f2key(float f) {
    unsigned b = __float_as_uint(f);
    return (b & 0x80000000u) ? ~b : (b | 0x80000000u);
}
__global__ void pool_init_k(unsigned* __restrict__ pool_u) {
    int i = blockIdx.x * 256 + threadIdx.x;
    if (i < N_GRAPHS * 128) pool_u[i] = f2key(-3.402823466e38f * 2.0f);  // -inf key
}
__global__ void norm_pool_k(const float* __restrict__ y, const float* __restrict__ scale,
                            const float* __restrict__ shift, const int* __restrict__ batch,
                            unsigned* __restrict__ pool_u, int N) {
    int idx = blockIdx.x * 256 + threadIdx.x;
    if (idx >= N * 128) return;
    int n = idx >> 7, c = idx & 127;
    float v = y[idx] * scale[c] + shift[c];
    atomicMax(&pool_u[batch[n] * 128 + c], f2key(v));
}
__global__ void pool_write_k(const unsigned* __restrict__ pool_u, float* __restrict__ out) {
    int i = blockIdx.x * 256 + threadIdx.x;
    if (i < N_GRAPHS * 128) {
        unsigned u = pool_u[i];
        unsigned b = (u & 0x80000000u) ? (u & 0x7FFFFFFFu) : ~u;
        out[i] = __uint_as_float(b);
    }
}

// ================================================================ launcher
extern "C" void kernel_launch(void* const* d_in, const int* in_sizes, int n_in,
                              void* d_out, int out_size, void* d_ws, size_t ws_size,
                              hipStream_t stream) {
    const int N = N_NODES, E = N_EDGES;
    const float* x_ppi = (const float*)d_in[0];
    const int* edge = (const int*)d_in[1];
    const int* batch = (const int*)d_in[2];
    const float* W1 = (const float*)d_in[3];
    const float* a_src1 = (const float*)d_in[4];
    const float* a_dst1 = (const float*)d_in[5];
    const float* b_gat1 = (const float*)d_in[6];
    const float* lw1 = (const float*)d_in[7];
    const float* lb1 = (const float*)d_in[8];
    const float* W2 = (const float*)d_in[9];
    const float* a_src2 = (const float*)d_in[10];
    const float* a_dst2 = (const float*)d_in[11];
    const float* b_gat2 = (const float*)d_in[12];
    const float* lw2 = (const float*)d_in[13];
    const float* lb2 = (const float*)d_in[14];
    const float* W3 = (const float*)d_in[15];
    const float* a_src3 = (const float*)d_in[16];
    const float* a_dst3 = (const float*)d_in[17];
    const float* b_gat3 = (const float*)d_in[18];
    const float* lw3 = (const float*)d_in[19];
    const float* lb3 = (const float*)d_in[20];
    const float* bn_gamma = (const float*)d_in[21];
    const float* bn_beta = (const float*)d_in[22];

    const int* src = edge;
    const int* dst = edge + E;

    // workspace carve-up (256B aligned)
    size_t off = 0;
    auto alloc = [&](size_t bytes) {
        size_t o = off;
        off = (off + bytes + 255) & ~(size_t)255;
        return o;
    };
    char* ws = (char*)d_ws;
    float* x_cur = (float*)(ws + alloc((size_t)N * 256 * 4));
    float* h_buf = (float*)(ws + alloc((size_t)N * 768 * 4));
    float* lin = (float*)(ws + alloc((size_t)N * 256 * 4));  // reused as y after L3
    float* x_res = (float*)(ws + alloc((size_t)N * 128 * 4));
    float* as_ = (float*)(ws + alloc((size_t)N * 6 * 4));
    float* ad_ = (float*)(ws + alloc((size_t)N * 6 * 4));
    int* deg = (int*)(ws + alloc((size_t)(N + 1) * 4));
    int* offs = (int*)(ws + alloc((size_t)(N + 1) * 4));
    int* cursor = (int*)(ws + alloc((size_t)(N + 1) * 4));
    int* csr_src = (int*)(ws + alloc((size_t)E * 4));
    int* csr_eid = (int*)(ws + alloc((size_t)E * 4));
    float* bn_sums = (float*)(ws + alloc(128 * 4));
    float* bn_mu = (float*)(ws + alloc(128 * 4));
    float* bn_scale = (float*)(ws + alloc(128 * 4));
    float* bn_shift = (float*)(ws + alloc(128 * 4));
    unsigned* pool_u = (unsigned*)(ws + alloc((size_t)N_GRAPHS * 128 * 4));

    float* out_pool = (float*)d_out;              // [64*128]
    float* out_att = (float*)d_out + N_GRAPHS * 128;  // [E*6]

    // ---- CSR
    hipMemsetAsync(deg, 0, (size_t)N * 4, stream);
    hist_k<<<(E + 255) / 256, 256, 0, stream>>>(dst, deg, E);
    scan_k<<<1, 1024, 0, stream>>>(deg, offs, cursor, N);
    scatter_k<<<(E + 255) / 256, 256, 0, stream>>>(src, dst, cursor, csr_src, csr_eid, E);

    dim3 g256(4, 313), g768(12, 313), g128(2, 313);

    // ---- Layer 1 (in=8)
    gemm_k<<<g256, 256, 0, stream>>>(x_ppi, W1, h_buf, nullptr, N, 256, 8);
    gemm_k<<<g256, 256, 0, stream>>>(x_ppi, lw1, lin, lb1, N, 256, 8);
    attn_k<<<N, 64, 0, stream>>>(h_buf, a_src1, a_dst1, as_, ad_, 4, 64);
    agg_concat_k<<<N, 256, 0, stream>>>(h_buf, as_, ad_, offs, csr_src, lin, b_gat1, x_cur);

    // ---- Layer 2 (256 -> 256)
    gemm_k<<<g256, 256, 0, stream>>>(x_cur, W2, h_buf, nullptr, N, 256, 256);
    gemm_k<<<g256, 256, 0, stream>>>(x_cur, lw2, lin, lb2, N, 256, 256);
    attn_k<<<N, 64, 0, stream>>>(h_buf, a_src2, a_dst2, as_, ad_, 4, 64);
    agg_concat_k<<<N, 256, 0, stream>>>(h_buf, as_, ad_, offs, csr_src, lin, b_gat2, x_cur);

    // ---- Layer 3 (256 -> 6x128, mean) + residual
    gemm_k<<<g768, 256, 0, stream>>>(x_cur, W3, h_buf, nullptr, N, 768, 256);
    gemm_k<<<g128, 256, 0, stream>>>(x_cur, lw3, x_res, lb3, N, 128, 256);
    attn_k<<<N, 64, 0, stream>>>(h_buf, a_src3, a_dst3, as_, ad_, 6, 128);
    float* y = lin;  // reuse
    agg_mean_k<<<N, 256, 0, stream>>>(h_buf, as_, ad_, offs, csr_src, csr_eid, x_res, b_gat3,
                                      y, out_att);

    // ---- BatchNorm (training stats, two-pass)
    hipMemsetAsync(bn_sums, 0, 128 * 4, stream);
    bn_pass1_k<<<160, 128, 0, stream>>>(y, bn_sums, N);
    bn_mu_k<<<1, 128, 0, stream>>>(bn_sums, bn_mu, N);
    hipMemsetAsync(bn_sums, 0, 128 * 4, stream);
    bn_pass2_k<<<160, 128, 0, stream>>>(y, bn_mu, bn_sums, N);
    bn_scale_k<<<1, 128, 0, stream>>>(bn_sums, bn_mu, bn_gamma, bn_beta, bn_scale, bn_shift, N);

    // ---- normalize + global max pool
    pool_init_k<<<(N_GRAPHS * 128 + 255) / 256, 256, 0, stream>>>(pool_u);
    norm_pool_k<<<((size_t)N * 128 + 255) / 256, 256, 0, stream>>>(y, bn_scale, bn_shift, batch,
                                                                   pool_u, N);
    pool_write_k<<<(N_GRAPHS * 128 + 255) / 256, 256, 0, stream>>>(pool_u, out_pool);
}

// Round 2
// 707.726 us; speedup vs baseline: 1.2876x; 1.2876x over previous
//
#include <hip/hip_runtime.h>
#include <hip/hip_bf16.h>
#include <math.h>

#define N_NODES 20000
#define N_EDGES 320000
#define N_GRAPHS 64

typedef __bf16 bf16_t;
typedef bf16_t bf16x8 __attribute__((ext_vector_type(8)));
typedef float f32x4 __attribute__((ext_vector_type(4)));

// ---------------------------------------------------------------- CSR build
__global__ void hist_k(const int* __restrict__ dst, int* __restrict__ deg, int E) {
    int e = blockIdx.x * 256 + threadIdx.x;
    if (e < E) atomicAdd(&deg[dst[e]], 1);
}

__global__ void scan_k(const int* __restrict__ deg, int* __restrict__ offs,
                       int* __restrict__ cursor, int n) {
    __shared__ int buf[1024];
    __shared__ int s_carry;
    int tid = threadIdx.x;
    if (tid == 0) s_carry = 0;
    __syncthreads();
    for (int base = 0; base < n; base += 1024) {
        int carry = s_carry;
        int i = base + tid;
        int v = (i < n) ? deg[i] : 0;
        buf[tid] = v;
        __syncthreads();
        for (int off = 1; off < 1024; off <<= 1) {
            int t = (tid >= off) ? buf[tid - off] : 0;
            __syncthreads();
            buf[tid] += t;
            __syncthreads();
        }
        int incl = buf[tid];
        if (i < n) { int ex = carry + incl - v; offs[i] = ex; cursor[i] = ex; }
        if (tid == 1023) s_carry = carry + incl;
        __syncthreads();
    }
    if (tid == 0) offs[n] = s_carry;
}

__global__ void scatter_k(const int* __restrict__ src, const int* __restrict__ dst,
                          int* __restrict__ cursor, int* __restrict__ csr_src,
                          int* __restrict__ csr_eid, int E) {
    int e = blockIdx.x * 256 + threadIdx.x;
    if (e < E) {
        int d = dst[e];
        int p = atomicAdd(&cursor[d], 1);
        csr_src[p] = src[e];
        csr_eid[p] = e;
    }
}

// --------------------------------------------- weight transpose + bf16 cast
// Bt[n][k] = bf16(W[k][n]).  K,N multiples of 32.
__global__ __launch_bounds__(256) void wt_k(const float* __restrict__ W,
                                            bf16_t* __restrict__ Bt, int K, int N) {
    __shared__ float t[32][33];
    int k0 = blockIdx.y * 32, n0 = blockIdx.x * 32;
    int tx = threadIdx.x & 31, ty = threadIdx.x >> 5;  // ty 0..7
    for (int i = ty; i < 32; i += 8) t[i][tx] = W[(size_t)(k0 + i) * N + n0 + tx];
    __syncthreads();
    for (int i = ty; i < 32; i += 8)
        Bt[(size_t)(n0 + i) * K + k0 + tx] = (bf16_t)t[tx][i];
}

// ---------------------------------------------------------------- fp32 GEMM
// Used only for layer 1 (K=8). C[M,N] = A[M,K] @ B[K,N] (+bias).
__global__ __launch_bounds__(256) void gemm_k(const float* __restrict__ A,
                                              const float* __restrict__ B,
                                              float* __restrict__ C,
                                              const float* __restrict__ bias,
                                              int M, int N, int K) {
    __shared__ float As[16][65];
    __shared__ float Bs[16][64];
    int tid = threadIdx.x;
    int tx = tid & 15, ty = tid >> 4;
    int row0 = blockIdx.y * 64, col0 = blockIdx.x * 64;
    float acc[4][4] = {};
    for (int k0 = 0; k0 < K; k0 += 16) {
        #pragma unroll
        for (int i = 0; i < 4; ++i) {
            int idx = tid + i * 256;
            int m = idx >> 4, kk = idx & 15;
            int gm = row0 + m, gk = k0 + kk;
            As[kk][m] = (gm < M && gk < K) ? A[(size_t)gm * K + gk] : 0.f;
        }
        #pragma unroll
        for (int i = 0; i < 4; ++i) {
            int idx = tid + i * 256;
            int kk = idx >> 6, n = idx & 63;
            int gk = k0 + kk, gn = col0 + n;
            Bs[kk][n] = (gk < K && gn < N) ? B[(size_t)gk * N + gn] : 0.f;
        }
        __syncthreads();
        #pragma unroll
        for (int kk = 0; kk < 16; ++kk) {
            float a[4], b[4];
            #pragma unroll
            for (int i = 0; i < 4; ++i) a[i] = As[kk][ty * 4 + i];
            #pragma unroll
            for (int j = 0; j < 4; ++j) b[j] = Bs[kk][tx * 4 + j];
            #pragma unroll
            for (int i = 0; i < 4; ++i)
                #pragma unroll
                for (int j = 0; j < 4; ++j) acc[i][j] += a[i] * b[j];
        }
        __syncthreads();
    }
    #pragma unroll
    for (int i = 0; i < 4; ++i) {
        int gm = row0 + ty * 4 + i;
        if (gm >= M) continue;
        #pragma unroll
        for (int j = 0; j < 4; ++j) {
            int gn = col0 + tx * 4 + j;
            if (gn < N) C[(size_t)gm * N + gn] = acc[i][j] + (bias ? bias[gn] : 0.f);
        }
    }
}

// ------------------------------------------------------------ bf16 MFMA GEMM
// C[M,N] fp32 = A[M,K] (bf16, row-major) @ Bt[N,K]^T (bf16), +bias.
// 128x128 tile, 256 threads = 4 waves in 2x2, 64x64 per wave via 4x4 of
// mfma_f32_16x16x32_bf16. K % 32 == 0, N % 128 == 0.
__global__ __launch_bounds__(256) void gemm_bf16_k(
    const bf16_t* __restrict__ A, const bf16_t* __restrict__ Bt,
    float* __restrict__ C, const float* __restrict__ bias, int M, int N, int K) {
    __shared__ bf16_t As[128][40];  // padded stride: 80B rows -> 2-way max
    __shared__ bf16_t Bs[128][40];
    int tid = threadIdx.x;
    int row0 = blockIdx.y * 128, col0 = blockIdx.x * 128;
    int wave = tid >> 6, lane = tid & 63, quad = lane >> 4, l16 = lane & 15;
    int wm = wave >> 1, wn = wave & 1;
    f32x4 acc[4][4] = {};
    int sr = tid >> 2;         // 0..63
    int sc = (tid & 3) * 8;    // 0,8,16,24
    for (int k0 = 0; k0 < K; k0 += 32) {
        #pragma unroll
        for (int half = 0; half < 2; ++half) {
            int r = sr + half * 64;
            int gm = row0 + r;
            bf16x8 v = {};
            if (gm < M) v = *(const bf16x8*)&A[(size_t)gm * K + k0 + sc];
            *(bf16x8*)&As[r][sc] = v;
            int gn = col0 + r;
            bf16x8 w = {};
            if (gn < N) w = *(const bf16x8*)&Bt[(size_t)gn * K + k0 + sc];
            *(bf16x8*)&Bs[r][sc] = w;
        }
        __syncthreads();
        bf16x8 af[4], bfr[4];
        #pragma unroll
        for (int i = 0; i < 4; ++i) {
            af[i] = *(const bf16x8*)&As[wm * 64 + i * 16 + l16][quad * 8];
            bfr[i] = *(const bf16x8*)&Bs[wn * 64 + i * 16 + l16][quad * 8];
        }
        #pragma unroll
        for (int i = 0; i < 4; ++i)
            #pragma unroll
            for (int j = 0; j < 4; ++j)
                acc[i][j] = __builtin_amdgcn_mfma_f32_16x16x32_bf16(af[i], bfr[j],
                                                                   acc[i][j], 0, 0, 0);
        __syncthreads();
    }
    #pragma unroll
    for (int i = 0; i < 4; ++i) {
        int base_m = row0 + wm * 64 + i * 16 + quad * 4;
        #pragma unroll
        for (int j = 0; j < 4; ++j) {
            int gn = col0 + wn * 64 + j * 16 + l16;
            float bv = bias ? bias[gn] : 0.f;
            #pragma unroll
            for (int r = 0; r < 4; ++r) {
                int gm = base_m + r;
                if (gm < M) C[(size_t)gm * N + gn] = acc[i][j][r] + bv;
            }
        }
    }
}

// ------------------------------------------------- attention scores as/ad
__global__ void attn_k(const float* __restrict__ h, const float* __restrict__ a_s,
                       const float* __restrict__ a_d, float* __restrict__ as_,
                       float* __restrict__ ad_, int H, int C) {
    int j = blockIdx.x;
    int lane = threadIdx.x;  // 64
    const float* row = h + (size_t)j * H * C;
    for (int hh = 0; hh < H; ++hh) {
        float ss = 0.f, dd = 0.f;
        for (int c = lane; c < C; c += 64) {
            float v = row[hh * C + c];
            ss += v * a_s[hh * C + c];
            dd += v * a_d[hh * C + c];
        }
        #pragma unroll
        for (int off = 32; off; off >>= 1) {
            ss += __shfl_xor(ss, off);
            dd += __shfl_xor(dd, off);
        }
        if (lane == 0) { as_[j * H + hh] = ss; ad_[j * H + hh] = dd; }
    }
}

__device__ __forceinline__ float leaky02(float v) { return v > 0.f ? v : 0.2f * v; }

// ------------------------------------------- aggregation, concat (H=4,C=64)
// xb[j,t] = bf16(relu( sum_e alpha[e,h]*h[src,t] + bgat[t] + lin[j,t] ))
__global__ __launch_bounds__(256) void agg_concat_k(
    const float* __restrict__ h, const float* __restrict__ as_,
    const float* __restrict__ ad_, const int* __restrict__ offs,
    const int* __restrict__ csr_src, const float* __restrict__ lin,
    const float* __restrict__ bgat, bf16_t* __restrict__ xb) {
    int j = blockIdx.x;
    int tid = threadIdx.x;  // 256
    int o0 = offs[j], deg = offs[j + 1] - o0;
    __shared__ float s_m[4], s_d[4], s_adj[4];
    __shared__ float s_alpha[64 * 4];
    __shared__ int s_src[64];
    if (tid < 4) s_adj[tid] = ad_[j * 4 + tid];
    __syncthreads();
    if (tid < 64) {
        float mx[4] = {-3.4e38f, -3.4e38f, -3.4e38f, -3.4e38f};
        for (int e = tid; e < deg; e += 64) {
            int s = csr_src[o0 + e];
            #pragma unroll
            for (int hh = 0; hh < 4; ++hh) {
                float v = leaky02(as_[s * 4 + hh] + s_adj[hh]);
                mx[hh] = fmaxf(mx[hh], v);
            }
        }
        #pragma unroll
        for (int off = 32; off; off >>= 1)
            #pragma unroll
            for (int hh = 0; hh < 4; ++hh) mx[hh] = fmaxf(mx[hh], __shfl_xor(mx[hh], off));
        float sm[4] = {0.f, 0.f, 0.f, 0.f};
        for (int e = tid; e < deg; e += 64) {
            int s = csr_src[o0 + e];
            #pragma unroll
            for (int hh = 0; hh < 4; ++hh) {
                float v = leaky02(as_[s * 4 + hh] + s_adj[hh]);
                sm[hh] += __expf(v - mx[hh]);
            }
        }
        #pragma unroll
        for (int off = 32; off; off >>= 1)
            #pragma unroll
            for (int hh = 0; hh < 4; ++hh) sm[hh] += __shfl_xor(sm[hh], off);
        if (tid == 0) {
            #pragma unroll
            for (int hh = 0; hh < 4; ++hh) { s_m[hh] = mx[hh]; s_d[hh] = sm[hh]; }
        }
    }
    __syncthreads();
    int myh = tid >> 6;
    float acc = 0.f;
    for (int e0 = 0; e0 < deg; e0 += 64) {
        int ne = min(64, deg - e0);
        {
            int e_l = tid >> 2, ah = tid & 3;
            if (e_l < ne) {
                int s = csr_src[o0 + e0 + e_l];
                if (ah == 0) s_src[e_l] = s;
                float v = leaky02(as_[s * 4 + ah] + s_adj[ah]);
                s_alpha[e_l * 4 + ah] = __expf(v - s_m[ah]) / (s_d[ah] + 1e-16f);
            }
        }
        __syncthreads();
        for (int e_l = 0; e_l < ne; ++e_l) {
            int s = s_src[e_l];
            acc += s_alpha[e_l * 4 + myh] * h[(size_t)s * 256 + tid];
        }
        __syncthreads();
    }
    float v = fmaxf(acc + bgat[tid] + lin[(size_t)j * 256 + tid], 0.f);
    xb[(size_t)j * 256 + tid] = (bf16_t)v;
}

// --------------------------------------- aggregation, mean (H=6,C=128) + att
__global__ __launch_bounds__(256) void agg_mean_k(
    const float* __restrict__ h, const float* __restrict__ as_,
    const float* __restrict__ ad_, const int* __restrict__ offs,
    const int* __restrict__ csr_src, const int* __restrict__ csr_eid,
    const float* __restrict__ xres, const float* __restrict__ bgat,
    float* __restrict__ y, float* __restrict__ att) {
    int j = blockIdx.x;
    int tid = threadIdx.x;  // 256
    int o0 = offs[j], deg = offs[j + 1] - o0;
    __shared__ float s_m[6], s_d[6], s_adj[6];
    __shared__ float s_alpha[32 * 6];
    __shared__ int s_src[32];
    if (tid < 6) s_adj[tid] = ad_[j * 6 + tid];
    __syncthreads();
    if (tid < 64) {
        float mx[6], sm[6];
        #pragma unroll
        for (int hh = 0; hh < 6; ++hh) { mx[hh] = -3.4e38f; sm[hh] = 0.f; }
        for (int e = tid; e < deg; e += 64) {
            int s = csr_src[o0 + e];
            #pragma unroll
            for (int hh = 0; hh < 6; ++hh) {
                float v = leaky02(as_[s * 6 + hh] + s_adj[hh]);
                mx[hh] = fmaxf(mx[hh], v);
            }
        }
        #pragma unroll
        for (int off = 32; off; off >>= 1)
            #pragma unroll
            for (int hh = 0; hh < 6; ++hh) mx[hh] = fmaxf(mx[hh], __shfl_xor(mx[hh], off));
        for (int e = tid; e < deg; e += 64) {
            int s = csr_src[o0 + e];
            #pragma unroll
            for (int hh = 0; hh < 6; ++hh) {
                float v = leaky02(as_[s * 6 + hh] + s_adj[hh]);
                sm[hh] += __expf(v - mx[hh]);
            }
        }
        #pragma unroll
        for (int off = 32; off; off >>= 1)
            #pragma unroll
            for (int hh = 0; hh < 6; ++hh) sm[hh] += __shfl_xor(sm[hh], off);
        if (tid == 0) {
            #pragma unroll
            for (int hh = 0; hh < 6; ++hh) { s_m[hh] = mx[hh]; s_d[hh] = sm[hh]; }
        }
    }
    __syncthreads();
    float acc = 0.f;
    for (int e0 = 0; e0 < deg; e0 += 32) {
        int ne = min(32, deg - e0);
        if (tid < 192) {
            int e_l = tid / 6, ah = tid - e_l * 6;
            if (e_l < ne) {
                int p = o0 + e0 + e_l;
                int s = csr_src[p];
                if (ah == 0) s_src[e_l] = s;
                float v = leaky02(as_[s * 6 + ah] + s_adj[ah]);
                float al = __expf(v - s_m[ah]) / (s_d[ah] + 1e-16f);
                s_alpha[e_l * 6 + ah] = al;
                att[(size_t)csr_eid[p] * 6 + ah] = al;
            }
        }
        __syncthreads();
        if (tid < 128) {
            for (int e_l = 0; e_l < ne; ++e_l) {
                int s = s_src[e_l];
                const float* hr = h + (size_t)s * 768 + tid;
                #pragma unroll
                for (int hh = 0; hh < 6; ++hh) acc += s_alpha[e_l * 6 + hh] * hr[hh * 128];
            }
        }
        __syncthreads();
    }
    if (tid < 128)
        y[(size_t)j * 128 + tid] =
            fmaxf(acc * (1.f / 6.f) + bgat[tid] + xres[(size_t)j * 128 + tid], 0.f);
}

// ---------------------------------------------------------------- BatchNorm
__global__ void bn_pass1_k(const float* __restrict__ y, float* __restrict__ sums, int N) {
    int c = threadIdx.x;  // 128
    float s = 0.f;
    for (int r = blockIdx.x; r < N; r += gridDim.x) s += y[(size_t)r * 128 + c];
    atomicAdd(&sums[c], s);
}
__global__ void bn_mu_k(const float* __restrict__ sums, float* __restrict__ mu, int N) {
    int c = threadIdx.x;
    mu[c] = sums[c] / (float)N;
}
__global__ void bn_pass2_k(const float* __restrict__ y, const float* __restrict__ mu,
                           float* __restrict__ sums, int N) {
    int c = threadIdx.x;
    float m = mu[c], s = 0.f;
    for (int r = blockIdx.x; r < N; r += gridDim.x) {
        float d = y[(size_t)r * 128 + c] - m;
        s += d * d;
    }
    atomicAdd(&sums[c], s);
}
__global__ void bn_scale_k(const float* __restrict__ sums, const float* __restrict__ mu,
                           const float* __restrict__ gamma, const float* __restrict__ beta,
                           float* __restrict__ scale, float* __restrict__ shift, int N) {
    int c = threadIdx.x;
    float var = sums[c] / (float)N;
    float inv = 1.0f / sqrtf(var + 1e-5f);
    float sc = inv * gamma[c];
    scale[c] = sc;
    shift[c] = beta[c] - mu[c] * sc;
}

// ---------------------------------------------------------------- max pool
__device__ __forceinline__ unsigned f2key(float f) {
    unsigned b = __float_as_uint(f);
    return (b & 0x80000000u) ? ~b : (b | 0x80000000u);
}
__global__ void pool_init_k(unsigned* __restrict__ pool_u) {
    int i = blockIdx.x * 256 + threadIdx.x;
    if (i < N_GRAPHS * 128) pool_u[i] = f2key(-3.402823466e38f * 2.0f);
}
__global__ void norm_pool_k(const float* __restrict__ y, const float* __restrict__ scale,
                            const float* __restrict__ shift, const int* __restrict__ batch,
                            unsigned* __restrict__ pool_u, int N) {
    int idx = blockIdx.x * 256 + threadIdx.x;
    if (idx >= N * 128) return;
    int n = idx >> 7, c = idx & 127;
    float v = y[idx] * scale[c] + shift[c];
    atomicMax(&pool_u[batch[n] * 128 + c], f2key(v));
}
__global__ void pool_write_k(const unsigned* __restrict__ pool_u, float* __restrict__ out) {
    int i = blockIdx.x * 256 + threadIdx.x;
    if (i < N_GRAPHS * 128) {
        unsigned u = pool_u[i];
        unsigned b = (u & 0x80000000u) ? (u & 0x7FFFFFFFu) : ~u;
        out[i] = __uint_as_float(b);
    }
}

// ================================================================ launcher
extern "C" void kernel_launch(void* const* d_in, const int* in_sizes, int n_in,
                              void* d_out, int out_size, void* d_ws, size_t ws_size,
                              hipStream_t stream) {
    const int N = N_NODES, E = N_EDGES;
    const float* x_ppi = (const float*)d_in[0];
    const int* edge = (const int*)d_in[1];
    const int* batch = (const int*)d_in[2];
    const float* W1 = (const float*)d_in[3];
    const float* a_src1 = (const float*)d_in[4];
    const float* a_dst1 = (const float*)d_in[5];
    const float* b_gat1 = (const float*)d_in[6];
    const float* lw1 = (const float*)d_in[7];
    const float* lb1 = (const float*)d_in[8];
    const float* W2 = (const float*)d_in[9];
    const float* a_src2 = (const float*)d_in[10];
    const float* a_dst2 = (const float*)d_in[11];
    const float* b_gat2 = (const float*)d_in[12];
    const float* lw2 = (const float*)d_in[13];
    const float* lb2 = (const float*)d_in[14];
    const float* W3 = (const float*)d_in[15];
    const float* a_src3 = (const float*)d_in[16];
    const float* a_dst3 = (const float*)d_in[17];
    const float* b_gat3 = (const float*)d_in[18];
    const float* lw3 = (const float*)d_in[19];
    const float* lb3 = (const float*)d_in[20];
    const float* bn_gamma = (const float*)d_in[21];
    const float* bn_beta = (const float*)d_in[22];

    const int* src = edge;
    const int* dst = edge + E;

    size_t off = 0;
    auto alloc = [&](size_t bytes) {
        size_t o = off;
        off = (off + bytes + 255) & ~(size_t)255;
        return o;
    };
    char* ws = (char*)d_ws;
    bf16_t* xb = (bf16_t*)(ws + alloc((size_t)N * 256 * 2));   // bf16 activations
    float* h_buf = (float*)(ws + alloc((size_t)N * 768 * 4));
    float* lin = (float*)(ws + alloc((size_t)N * 256 * 4));    // reused as y after L3
    float* x_res = (float*)(ws + alloc((size_t)N * 128 * 4));
    float* as_ = (float*)(ws + alloc((size_t)N * 6 * 4));
    float* ad_ = (float*)(ws + alloc((size_t)N * 6 * 4));
    int* deg = (int*)(ws + alloc((size_t)(N + 1) * 4));
    int* offs = (int*)(ws + alloc((size_t)(N + 1) * 4));
    int* cursor = (int*)(ws + alloc((size_t)(N + 1) * 4));
    int* csr_src = (int*)(ws + alloc((size_t)E * 4));
    int* csr_eid = (int*)(ws + alloc((size_t)E * 4));
    bf16_t* Wt2 = (bf16_t*)(ws + alloc((size_t)256 * 256 * 2));
    bf16_t* lwt2 = (bf16_t*)(ws + alloc((size_t)256 * 256 * 2));
    bf16_t* Wt3 = (bf16_t*)(ws + alloc((size_t)768 * 256 * 2));
    bf16_t* lwt3 = (bf16_t*)(ws + alloc((size_t)128 * 256 * 2));
    float* bn_sums = (float*)(ws + alloc(128 * 4));
    float* bn_mu = (float*)(ws + alloc(128 * 4));
    float* bn_scale = (float*)(ws + alloc(128 * 4));
    float* bn_shift = (float*)(ws + alloc(128 * 4));
    unsigned* pool_u = (unsigned*)(ws + alloc((size_t)N_GRAPHS * 128 * 4));

    float* out_pool = (float*)d_out;
    float* out_att = (float*)d_out + N_GRAPHS * 128;

    // ---- CSR + weight prep (independent)
    hipMemsetAsync(deg, 0, (size_t)N * 4, stream);
    hist_k<<<(E + 255) / 256, 256, 0, stream>>>(dst, deg, E);
    scan_k<<<1, 1024, 0, stream>>>(deg, offs, cursor, N);
    scatter_k<<<(E + 255) / 256, 256, 0, stream>>>(src, dst, cursor, csr_src, csr_eid, E);
    wt_k<<<dim3(8, 8), 256, 0, stream>>>(W2, Wt2, 256, 256);
    wt_k<<<dim3(8, 8), 256, 0, stream>>>(lw2, lwt2, 256, 256);
    wt_k<<<dim3(24, 8), 256, 0, stream>>>(W3, Wt3, 256, 768);
    wt_k<<<dim3(4, 8), 256, 0, stream>>>(lw3, lwt3, 256, 128);

    // ---- Layer 1 (in=8, fp32 GEMM — tiny K)
    gemm_k<<<dim3(4, 313), 256, 0, stream>>>(x_ppi, W1, h_buf, nullptr, N, 256, 8);
    gemm_k<<<dim3(4, 313), 256, 0, stream>>>(x_ppi, lw1, lin, lb1, N, 256, 8);
    attn_k<<<N, 64, 0, stream>>>(h_buf, a_src1, a_dst1, as_, ad_, 4, 64);
    agg_concat_k<<<N, 256, 0, stream>>>(h_buf, as_, ad_, offs, csr_src, lin, b_gat1, xb);

    // ---- Layer 2 (256 -> 256, bf16 MFMA)
    gemm_bf16_k<<<dim3(2, 157), 256, 0, stream>>>(xb, Wt2, h_buf, nullptr, N, 256, 256);
    gemm_bf16_k<<<dim3(2, 157), 256, 0, stream>>>(xb, lwt2, lin, lb2, N, 256, 256);
    attn_k<<<N, 64, 0, stream>>>(h_buf, a_src2, a_dst2, as_, ad_, 4, 64);
    agg_concat_k<<<N, 256, 0, stream>>>(h_buf, as_, ad_, offs, csr_src, lin, b_gat2, xb);

    // ---- Layer 3 (256 -> 6x128 mean + residual, bf16 MFMA)
    gemm_bf16_k<<<dim3(6, 157), 256, 0, stream>>>(xb, Wt3, h_buf, nullptr, N, 768, 256);
    gemm_bf16_k<<<dim3(1, 157), 256, 0, stream>>>(xb, lwt3, x_res, lb3, N, 128, 256);
    attn_k<<<N, 64, 0, stream>>>(h_buf, a_src3, a_dst3, as_, ad_, 6, 128);
    float* y = lin;  // reuse
    agg_mean_k<<<N, 256, 0, stream>>>(h_buf, as_, ad_, offs, csr_src, csr_eid, x_res, b_gat3,
                                      y, out_att);

    // ---- BatchNorm (training stats, two-pass)
    hipMemsetAsync(bn_sums, 0, 128 * 4, stream);
    bn_pass1_k<<<160, 128, 0, stream>>>(y, bn_sums, N);
    bn_mu_k<<<1, 128, 0, stream>>>(bn_sums, bn_mu, N);
    hipMemsetAsync(bn_sums, 0, 128 * 4, stream);
    bn_pass2_k<<<160, 128, 0, stream>>>(y, bn_mu, bn_sums, N);
    bn_scale_k<<<1, 128, 0, stream>>>(bn_sums, bn_mu, bn_gamma, bn_beta, bn_scale, bn_shift, N);

    // ---- normalize + global max pool
    pool_init_k<<<(N_GRAPHS * 128 + 255) / 256, 256, 0, stream>>>(pool_u);
    norm_pool_k<<<((size_t)N * 128 + 255) / 256, 256, 0, stream>>>(y, bn_scale, bn_shift, batch,
                                                                   pool_u, N);
    pool_write_k<<<(N_GRAPHS * 128 + 255) / 256, 256, 0, stream>>>(pool_u, out_pool);
}

// Round 3
// 649.842 us; speedup vs baseline: 1.4023x; 1.0891x over previous
//
#include <hip/hip_runtime.h>
#include <hip/hip_bf16.h>
#include <math.h>

#define N_NODES 20000
#define N_EDGES 320000
#define N_GRAPHS 64

typedef __bf16 bf16_t;
typedef bf16_t bf16x8 __attribute__((ext_vector_type(8)));
typedef bf16_t bf16x4 __attribute__((ext_vector_type(4)));
typedef bf16_t bf16x2 __attribute__((ext_vector_type(2)));
typedef float f32x4 __attribute__((ext_vector_type(4)));

// ---------------------------------------------------------------- CSR build
__global__ void hist_k(const int* __restrict__ dst, int* __restrict__ deg, int E) {
    int e = blockIdx.x * 256 + threadIdx.x;
    if (e < E) atomicAdd(&deg[dst[e]], 1);
}

__global__ void scan_k(const int* __restrict__ deg, int* __restrict__ offs,
                       int* __restrict__ cursor, int n) {
    __shared__ int buf[1024];
    __shared__ int s_carry;
    int tid = threadIdx.x;
    if (tid == 0) s_carry = 0;
    __syncthreads();
    for (int base = 0; base < n; base += 1024) {
        int carry = s_carry;
        int i = base + tid;
        int v = (i < n) ? deg[i] : 0;
        buf[tid] = v;
        __syncthreads();
        for (int off = 1; off < 1024; off <<= 1) {
            int t = (tid >= off) ? buf[tid - off] : 0;
            __syncthreads();
            buf[tid] += t;
            __syncthreads();
        }
        int incl = buf[tid];
        if (i < n) { int ex = carry + incl - v; offs[i] = ex; cursor[i] = ex; }
        if (tid == 1023) s_carry = carry + incl;
        __syncthreads();
    }
    if (tid == 0) offs[n] = s_carry;
}

__global__ void scatter_k(const int* __restrict__ src, const int* __restrict__ dst,
                          int* __restrict__ cursor, int* __restrict__ csr_src,
                          int* __restrict__ csr_eid, int E) {
    int e = blockIdx.x * 256 + threadIdx.x;
    if (e < E) {
        int d = dst[e];
        int p = atomicAdd(&cursor[d], 1);
        csr_src[p] = src[e];
        csr_eid[p] = e;
    }
}

// --------------------------------------------- weight transpose + bf16 cast
__global__ __launch_bounds__(256) void wt_k(const float* __restrict__ W,
                                            bf16_t* __restrict__ Bt, int K, int N) {
    __shared__ float t[32][33];
    int k0 = blockIdx.y * 32, n0 = blockIdx.x * 32;
    int tx = threadIdx.x & 31, ty = threadIdx.x >> 5;
    for (int i = ty; i < 32; i += 8) t[i][tx] = W[(size_t)(k0 + i) * N + n0 + tx];
    __syncthreads();
    for (int i = ty; i < 32; i += 8)
        Bt[(size_t)(n0 + i) * K + k0 + tx] = (bf16_t)t[tx][i];
}

// ---------------------------------------------------------------- fp32 GEMM
// Used only for layer 1 (K=8).
template <typename OUT>
__global__ __launch_bounds__(256) void gemm_k(const float* __restrict__ A,
                                              const float* __restrict__ B,
                                              OUT* __restrict__ C,
                                              const float* __restrict__ bias,
                                              int M, int N, int K) {
    __shared__ float As[16][65];
    __shared__ float Bs[16][64];
    int tid = threadIdx.x;
    int tx = tid & 15, ty = tid >> 4;
    int row0 = blockIdx.y * 64, col0 = blockIdx.x * 64;
    float acc[4][4] = {};
    for (int k0 = 0; k0 < K; k0 += 16) {
        #pragma unroll
        for (int i = 0; i < 4; ++i) {
            int idx = tid + i * 256;
            int m = idx >> 4, kk = idx & 15;
            int gm = row0 + m, gk = k0 + kk;
            As[kk][m] = (gm < M && gk < K) ? A[(size_t)gm * K + gk] : 0.f;
        }
        #pragma unroll
        for (int i = 0; i < 4; ++i) {
            int idx = tid + i * 256;
            int kk = idx >> 6, n = idx & 63;
            int gk = k0 + kk, gn = col0 + n;
            Bs[kk][n] = (gk < K && gn < N) ? B[(size_t)gk * N + gn] : 0.f;
        }
        __syncthreads();
        #pragma unroll
        for (int kk = 0; kk < 16; ++kk) {
            float a[4], b[4];
            #pragma unroll
            for (int i = 0; i < 4; ++i) a[i] = As[kk][ty * 4 + i];
            #pragma unroll
            for (int j = 0; j < 4; ++j) b[j] = Bs[kk][tx * 4 + j];
            #pragma unroll
            for (int i = 0; i < 4; ++i)
                #pragma unroll
                for (int j = 0; j < 4; ++j) acc[i][j] += a[i] * b[j];
        }
        __syncthreads();
    }
    #pragma unroll
    for (int i = 0; i < 4; ++i) {
        int gm = row0 + ty * 4 + i;
        if (gm >= M) continue;
        #pragma unroll
        for (int j = 0; j < 4; ++j) {
            int gn = col0 + tx * 4 + j;
            if (gn < N) C[(size_t)gm * N + gn] = (OUT)(acc[i][j] + (bias ? bias[gn] : 0.f));
        }
    }
}

// ------------------------------------------------------------ bf16 MFMA GEMM
template <typename OUT>
__global__ __launch_bounds__(256) void gemm_bf16_k(
    const bf16_t* __restrict__ A, const bf16_t* __restrict__ Bt,
    OUT* __restrict__ C, const float* __restrict__ bias, int M, int N, int K) {
    __shared__ bf16_t As[128][40];
    __shared__ bf16_t Bs[128][40];
    int tid = threadIdx.x;
    int row0 = blockIdx.y * 128, col0 = blockIdx.x * 128;
    int wave = tid >> 6, lane = tid & 63, quad = lane >> 4, l16 = lane & 15;
    int wm = wave >> 1, wn = wave & 1;
    f32x4 acc[4][4] = {};
    int sr = tid >> 2;
    int sc = (tid & 3) * 8;
    for (int k0 = 0; k0 < K; k0 += 32) {
        #pragma unroll
        for (int half = 0; half < 2; ++half) {
            int r = sr + half * 64;
            int gm = row0 + r;
            bf16x8 v = {};
            if (gm < M) v = *(const bf16x8*)&A[(size_t)gm * K + k0 + sc];
            *(bf16x8*)&As[r][sc] = v;
            int gn = col0 + r;
            bf16x8 w = {};
            if (gn < N) w = *(const bf16x8*)&Bt[(size_t)gn * K + k0 + sc];
            *(bf16x8*)&Bs[r][sc] = w;
        }
        __syncthreads();
        bf16x8 af[4], bfr[4];
        #pragma unroll
        for (int i = 0; i < 4; ++i) {
            af[i] = *(const bf16x8*)&As[wm * 64 + i * 16 + l16][quad * 8];
            bfr[i] = *(const bf16x8*)&Bs[wn * 64 + i * 16 + l16][quad * 8];
        }
        #pragma unroll
        for (int i = 0; i < 4; ++i)
            #pragma unroll
            for (int j = 0; j < 4; ++j)
                acc[i][j] = __builtin_amdgcn_mfma_f32_16x16x32_bf16(af[i], bfr[j],
                                                                   acc[i][j], 0, 0, 0);
        __syncthreads();
    }
    #pragma unroll
    for (int i = 0; i < 4; ++i) {
        int base_m = row0 + wm * 64 + i * 16 + quad * 4;
        #pragma unroll
        for (int j = 0; j < 4; ++j) {
            int gn = col0 + wn * 64 + j * 16 + l16;
            float bv = bias ? bias[gn] : 0.f;
            #pragma unroll
            for (int r = 0; r < 4; ++r) {
                int gm = base_m + r;
                if (gm < M) C[(size_t)gm * N + gn] = (OUT)(acc[i][j][r] + bv);
            }
        }
    }
}

// ------------------------------------------------- attention scores as/ad
// One wave per node; vectorized bf16x4 reads over the flat H*C row.
__global__ void attn_k(const bf16_t* __restrict__ h, const float* __restrict__ a_s,
                       const float* __restrict__ a_d, float* __restrict__ as_,
                       float* __restrict__ ad_, int H, int C) {
    int j = blockIdx.x;
    int lane = threadIdx.x;  // 64
    const bf16_t* row = h + (size_t)j * H * C;
    int HC = H * C;
    float ss[6] = {}, dd[6] = {};
    for (int f = lane * 4; f < HC; f += 256) {
        bf16x4 v = *(const bf16x4*)&row[f];
        f32x4 a = *(const f32x4*)&a_s[f];
        f32x4 d = *(const f32x4*)&a_d[f];
        int hh = f / C;
        float s0 = 0.f, d0 = 0.f;
        #pragma unroll
        for (int i = 0; i < 4; ++i) {
            float x = (float)v[i];
            s0 += x * a[i];
            d0 += x * d[i];
        }
        ss[hh] += s0;
        dd[hh] += d0;
    }
    for (int hh = 0; hh < H; ++hh) {
        float s = ss[hh], d = dd[hh];
        #pragma unroll
        for (int off = 32; off; off >>= 1) {
            s += __shfl_xor(s, off);
            d += __shfl_xor(d, off);
        }
        if (lane == 0) { as_[j * H + hh] = s; ad_[j * H + hh] = d; }
    }
}

__device__ __forceinline__ float leaky02(float v) { return v > 0.f ? v : 0.2f * v; }

// ------------------------------------------- aggregation, concat (H=4,C=64)
// xb[j,t] = bf16(relu( sum_e alpha[e,h]*h[src,t] + bgat[t] + lin[j,t] ))
// Gather pass: two edges in flight (tid>>7), each half covers 256 ch as bf16x2.
__global__ __launch_bounds__(256) void agg_concat_k(
    const bf16_t* __restrict__ h, const float* __restrict__ as_,
    const float* __restrict__ ad_, const int* __restrict__ offs,
    const int* __restrict__ csr_src, const float* __restrict__ lin,
    const float* __restrict__ bgat, bf16_t* __restrict__ xb) {
    int j = blockIdx.x;
    int tid = threadIdx.x;  // 256
    int o0 = offs[j], deg = offs[j + 1] - o0;
    __shared__ float s_m[4], s_d[4], s_adj[4];
    __shared__ float s_alpha[64 * 4];
    __shared__ int s_src[64];
    __shared__ float s_red[256];
    if (tid < 4) s_adj[tid] = ad_[j * 4 + tid];
    __syncthreads();
    if (tid < 64) {
        float mx[4] = {-3.4e38f, -3.4e38f, -3.4e38f, -3.4e38f};
        for (int e = tid; e < deg; e += 64) {
            int s = csr_src[o0 + e];
            #pragma unroll
            for (int hh = 0; hh < 4; ++hh) {
                float v = leaky02(as_[s * 4 + hh] + s_adj[hh]);
                mx[hh] = fmaxf(mx[hh], v);
            }
        }
        #pragma unroll
        for (int off = 32; off; off >>= 1)
            #pragma unroll
            for (int hh = 0; hh < 4; ++hh) mx[hh] = fmaxf(mx[hh], __shfl_xor(mx[hh], off));
        float sm[4] = {0.f, 0.f, 0.f, 0.f};
        for (int e = tid; e < deg; e += 64) {
            int s = csr_src[o0 + e];
            #pragma unroll
            for (int hh = 0; hh < 4; ++hh) {
                float v = leaky02(as_[s * 4 + hh] + s_adj[hh]);
                sm[hh] += __expf(v - mx[hh]);
            }
        }
        #pragma unroll
        for (int off = 32; off; off >>= 1)
            #pragma unroll
            for (int hh = 0; hh < 4; ++hh) sm[hh] += __shfl_xor(sm[hh], off);
        if (tid == 0) {
            #pragma unroll
            for (int hh = 0; hh < 4; ++hh) { s_m[hh] = mx[hh]; s_d[hh] = sm[hh]; }
        }
    }
    __syncthreads();
    int half = tid >> 7;         // 0/1: which edge parity this thread gathers
    int cpair = tid & 127;
    int c0 = cpair * 2;
    int myh = c0 >> 6;
    float acc0 = 0.f, acc1 = 0.f;
    for (int e0 = 0; e0 < deg; e0 += 64) {
        int ne = min(64, deg - e0);
        {
            int e_l = tid >> 2, ah = tid & 3;
            if (e_l < ne) {
                int s = csr_src[o0 + e0 + e_l];
                if (ah == 0) s_src[e_l] = s;
                float v = leaky02(as_[s * 4 + ah] + s_adj[ah]);
                s_alpha[e_l * 4 + ah] = __expf(v - s_m[ah]) / (s_d[ah] + 1e-16f);
            }
        }
        __syncthreads();
        for (int e_l = half; e_l < ne; e_l += 2) {
            int s = s_src[e_l];
            float al = s_alpha[e_l * 4 + myh];
            bf16x2 v = *(const bf16x2*)&h[(size_t)s * 256 + c0];
            acc0 += al * (float)v[0];
            acc1 += al * (float)v[1];
        }
        __syncthreads();
    }
    if (half == 1) { s_red[c0] = acc0; s_red[c0 + 1] = acc1; }
    __syncthreads();
    if (half == 0) {
        acc0 += s_red[c0];
        acc1 += s_red[c0 + 1];
        float v0 = fmaxf(acc0 + bgat[c0] + lin[(size_t)j * 256 + c0], 0.f);
        float v1 = fmaxf(acc1 + bgat[c0 + 1] + lin[(size_t)j * 256 + c0 + 1], 0.f);
        bf16x2 o = {(bf16_t)v0, (bf16_t)v1};
        *(bf16x2*)&xb[(size_t)j * 256 + c0] = o;
    }
}

// --------------------------------------- aggregation, mean (H=6,C=128) + att
// 192 gather threads: thread t owns head t>>5, channels 4*(t&31)..+3 (bf16x4).
__global__ __launch_bounds__(256) void agg_mean_k(
    const bf16_t* __restrict__ h, const float* __restrict__ as_,
    const float* __restrict__ ad_, const int* __restrict__ offs,
    const int* __restrict__ csr_src, const int* __restrict__ csr_eid,
    const float* __restrict__ xres, const float* __restrict__ bgat,
    float* __restrict__ y, float* __restrict__ att) {
    int j = blockIdx.x;
    int tid = threadIdx.x;  // 256
    int o0 = offs[j], deg = offs[j + 1] - o0;
    __shared__ float s_m[6], s_d[6], s_adj[6];
    __shared__ float s_alpha[32 * 6];
    __shared__ int s_src[32];
    __shared__ float s_red[6][128];
    if (tid < 6) s_adj[tid] = ad_[j * 6 + tid];
    __syncthreads();
    if (tid < 64) {
        float mx[6], sm[6];
        #pragma unroll
        for (int hh = 0; hh < 6; ++hh) { mx[hh] = -3.4e38f; sm[hh] = 0.f; }
        for (int e = tid; e < deg; e += 64) {
            int s = csr_src[o0 + e];
            #pragma unroll
            for (int hh = 0; hh < 6; ++hh) {
                float v = leaky02(as_[s * 6 + hh] + s_adj[hh]);
                mx[hh] = fmaxf(mx[hh], v);
            }
        }
        #pragma unroll
        for (int off = 32; off; off >>= 1)
            #pragma unroll
            for (int hh = 0; hh < 6; ++hh) mx[hh] = fmaxf(mx[hh], __shfl_xor(mx[hh], off));
        for (int e = tid; e < deg; e += 64) {
            int s = csr_src[o0 + e];
            #pragma unroll
            for (int hh = 0; hh < 6; ++hh) {
                float v = leaky02(as_[s * 6 + hh] + s_adj[hh]);
                sm[hh] += __expf(v - mx[hh]);
            }
        }
        #pragma unroll
        for (int off = 32; off; off >>= 1)
            #pragma unroll
            for (int hh = 0; hh < 6; ++hh) sm[hh] += __shfl_xor(sm[hh], off);
        if (tid == 0) {
            #pragma unroll
            for (int hh = 0; hh < 6; ++hh) { s_m[hh] = mx[hh]; s_d[hh] = sm[hh]; }
        }
    }
    __syncthreads();
    int ghh = tid >> 5;           // 0..7 (6 used)
    int c0 = (tid & 31) * 4;      // 0..124
    f32x4 acc = {};
    for (int e0 = 0; e0 < deg; e0 += 32) {
        int ne = min(32, deg - e0);
        if (tid < 192) {
            int e_l = tid / 6, ah = tid - e_l * 6;
            if (e_l < ne) {
                int p = o0 + e0 + e_l;
                int s = csr_src[p];
                if (ah == 0) s_src[e_l] = s;
                float v = leaky02(as_[s * 6 + ah] + s_adj[ah]);
                float al = __expf(v - s_m[ah]) / (s_d[ah] + 1e-16f);
                s_alpha[e_l * 6 + ah] = al;
                att[(size_t)csr_eid[p] * 6 + ah] = al;
            }
        }
        __syncthreads();
        if (tid < 192) {
            for (int e_l = 0; e_l < ne; ++e_l) {
                int s = s_src[e_l];
                float al = s_alpha[e_l * 6 + ghh];
                bf16x4 v = *(const bf16x4*)&h[(size_t)s * 768 + ghh * 128 + c0];
                #pragma unroll
                for (int i = 0; i < 4; ++i) acc[i] += al * (float)v[i];
            }
        }
        __syncthreads();
    }
    if (tid < 192) {
        #pragma unroll
        for (int i = 0; i < 4; ++i) s_red[ghh][c0 + i] = acc[i];
    }
    __syncthreads();
    if (tid < 128) {
        float s = 0.f;
        #pragma unroll
        for (int hh = 0; hh < 6; ++hh) s += s_red[hh][tid];
        y[(size_t)j * 128 + tid] =
            fmaxf(s * (1.f / 6.f) + bgat[tid] + xres[(size_t)j * 128 + tid], 0.f);
    }
}

// ---------------------------------------------------------------- BatchNorm
// single pass: sums[0..127]=sum, sums[128..255]=sumsq
__global__ void bn_stats_k(const float* __restrict__ y, float* __restrict__ sums, int N) {
    int c = threadIdx.x;  // 128
    float s = 0.f, q = 0.f;
    for (int r = blockIdx.x; r < N; r += gridDim.x) {
        float v = y[(size_t)r * 128 + c];
        s += v;
        q += v * v;
    }
    atomicAdd(&sums[c], s);
    atomicAdd(&sums[128 + c], q);
}
__global__ void bn_scale_k(const float* __restrict__ sums, const float* __restrict__ gamma,
                           const float* __restrict__ beta, float* __restrict__ scale,
                           float* __restrict__ shift, int N) {
    int c = threadIdx.x;
    float mu = sums[c] / (float)N;
    float var = fmaxf(sums[128 + c] / (float)N - mu * mu, 0.f);
    float inv = rsqrtf(var + 1e-5f) * gamma[c];
    scale[c] = inv;
    shift[c] = beta[c] - mu * inv;
}

// ---------------------------------------------------------------- max pool
__device__ __forceinline__ unsigned f2key(float f) {
    unsigned b = __float_as_uint(f);
    return (b & 0x80000000u) ? ~b : (b | 0x80000000u);
}
__global__ void pool_init_k(unsigned* __restrict__ pool_u) {
    int i = blockIdx.x * 256 + threadIdx.x;
    if (i < N_GRAPHS * 128) pool_u[i] = f2key(-3.402823466e38f * 2.0f);
}
__global__ void norm_pool_k(const float* __restrict__ y, const float* __restrict__ scale,
                            const float* __restrict__ shift, const int* __restrict__ batch,
                            unsigned* __restrict__ pool_u, int N) {
    int idx = blockIdx.x * 256 + threadIdx.x;
    if (idx >= N * 128) return;
    int n = idx >> 7, c = idx & 127;
    float v = y[idx] * scale[c] + shift[c];
    atomicMax(&pool_u[batch[n] * 128 + c], f2key(v));
}
__global__ void pool_write_k(const unsigned* __restrict__ pool_u, float* __restrict__ out) {
    int i = blockIdx.x * 256 + threadIdx.x;
    if (i < N_GRAPHS * 128) {
        unsigned u = pool_u[i];
        unsigned b = (u & 0x80000000u) ? (u & 0x7FFFFFFFu) : ~u;
        out[i] = __uint_as_float(b);
    }
}

// ================================================================ launcher
extern "C" void kernel_launch(void* const* d_in, const int* in_sizes, int n_in,
                              void* d_out, int out_size, void* d_ws, size_t ws_size,
                              hipStream_t stream) {
    const int N = N_NODES, E = N_EDGES;
    const float* x_ppi = (const float*)d_in[0];
    const int* edge = (const int*)d_in[1];
    const int* batch = (const int*)d_in[2];
    const float* W1 = (const float*)d_in[3];
    const float* a_src1 = (const float*)d_in[4];
    const float* a_dst1 = (const float*)d_in[5];
    const float* b_gat1 = (const float*)d_in[6];
    const float* lw1 = (const float*)d_in[7];
    const float* lb1 = (const float*)d_in[8];
    const float* W2 = (const float*)d_in[9];
    const float* a_src2 = (const float*)d_in[10];
    const float* a_dst2 = (const float*)d_in[11];
    const float* b_gat2 = (const float*)d_in[12];
    const float* lw2 = (const float*)d_in[13];
    const float* lb2 = (const float*)d_in[14];
    const float* W3 = (const float*)d_in[15];
    const float* a_src3 = (const float*)d_in[16];
    const float* a_dst3 = (const float*)d_in[17];
    const float* b_gat3 = (const float*)d_in[18];
    const float* lw3 = (const float*)d_in[19];
    const float* lb3 = (const float*)d_in[20];
    const float* bn_gamma = (const float*)d_in[21];
    const float* bn_beta = (const float*)d_in[22];

    const int* src = edge;
    const int* dst = edge + E;

    size_t off = 0;
    auto alloc = [&](size_t bytes) {
        size_t o = off;
        off = (off + bytes + 255) & ~(size_t)255;
        return o;
    };
    char* ws = (char*)d_ws;
    bf16_t* xb = (bf16_t*)(ws + alloc((size_t)N * 256 * 2));     // bf16 activations
    bf16_t* hb = (bf16_t*)(ws + alloc((size_t)N * 768 * 2));     // bf16 h (all layers)
    float* lin = (float*)(ws + alloc((size_t)N * 256 * 4));      // reused as y after L3
    float* x_res = (float*)(ws + alloc((size_t)N * 128 * 4));
    float* as_ = (float*)(ws + alloc((size_t)N * 6 * 4));
    float* ad_ = (float*)(ws + alloc((size_t)N * 6 * 4));
    int* deg = (int*)(ws + alloc((size_t)(N + 1) * 4));
    int* offs = (int*)(ws + alloc((size_t)(N + 1) * 4));
    int* cursor = (int*)(ws + alloc((size_t)(N + 1) * 4));
    int* csr_src = (int*)(ws + alloc((size_t)E * 4));
    int* csr_eid = (int*)(ws + alloc((size_t)E * 4));
    bf16_t* Wt2 = (bf16_t*)(ws + alloc((size_t)256 * 256 * 2));
    bf16_t* lwt2 = (bf16_t*)(ws + alloc((size_t)256 * 256 * 2));
    bf16_t* Wt3 = (bf16_t*)(ws + alloc((size_t)768 * 256 * 2));
    bf16_t* lwt3 = (bf16_t*)(ws + alloc((size_t)128 * 256 * 2));
    float* bn_sums = (float*)(ws + alloc(256 * 4));
    float* bn_scale = (float*)(ws + alloc(128 * 4));
    float* bn_shift = (float*)(ws + alloc(128 * 4));
    unsigned* pool_u = (unsigned*)(ws + alloc((size_t)N_GRAPHS * 128 * 4));

    float* out_pool = (float*)d_out;
    float* out_att = (float*)d_out + N_GRAPHS * 128;

    // ---- CSR + weight prep (independent)
    hipMemsetAsync(deg, 0, (size_t)N * 4, stream);
    hist_k<<<(E + 255) / 256, 256, 0, stream>>>(dst, deg, E);
    scan_k<<<1, 1024, 0, stream>>>(deg, offs, cursor, N);
    scatter_k<<<(E + 255) / 256, 256, 0, stream>>>(src, dst, cursor, csr_src, csr_eid, E);
    wt_k<<<dim3(8, 8), 256, 0, stream>>>(W2, Wt2, 256, 256);
    wt_k<<<dim3(8, 8), 256, 0, stream>>>(lw2, lwt2, 256, 256);
    wt_k<<<dim3(24, 8), 256, 0, stream>>>(W3, Wt3, 256, 768);
    wt_k<<<dim3(4, 8), 256, 0, stream>>>(lw3, lwt3, 256, 128);

    // ---- Layer 1 (in=8, fp32 GEMM — tiny K)
    gemm_k<bf16_t><<<dim3(4, 313), 256, 0, stream>>>(x_ppi, W1, hb, nullptr, N, 256, 8);
    gemm_k<float><<<dim3(4, 313), 256, 0, stream>>>(x_ppi, lw1, lin, lb1, N, 256, 8);
    attn_k<<<N, 64, 0, stream>>>(hb, a_src1, a_dst1, as_, ad_, 4, 64);
    agg_concat_k<<<N, 256, 0, stream>>>(hb, as_, ad_, offs, csr_src, lin, b_gat1, xb);

    // ---- Layer 2 (256 -> 256, bf16 MFMA)
    gemm_bf16_k<bf16_t><<<dim3(2, 157), 256, 0, stream>>>(xb, Wt2, hb, nullptr, N, 256, 256);
    gemm_bf16_k<float><<<dim3(2, 157), 256, 0, stream>>>(xb, lwt2, lin, lb2, N, 256, 256);
    attn_k<<<N, 64, 0, stream>>>(hb, a_src2, a_dst2, as_, ad_, 4, 64);
    agg_concat_k<<<N, 256, 0, stream>>>(hb, as_, ad_, offs, csr_src, lin, b_gat2, xb);

    // ---- Layer 3 (256 -> 6x128 mean + residual, bf16 MFMA)
    gemm_bf16_k<bf16_t><<<dim3(6, 157), 256, 0, stream>>>(xb, Wt3, hb, nullptr, N, 768, 256);
    gemm_bf16_k<float><<<dim3(1, 157), 256, 0, stream>>>(xb, lwt3, x_res, lb3, N, 128, 256);
    attn_k<<<N, 64, 0, stream>>>(hb, a_src3, a_dst3, as_, ad_, 6, 128);
    float* y = lin;  // reuse
    agg_mean_k<<<N, 256, 0, stream>>>(hb, as_, ad_, offs, csr_src, csr_eid, x_res, b_gat3,
                                      y, out_att);

    // ---- BatchNorm (training stats, fused sum+sumsq pass)
    hipMemsetAsync(bn_sums, 0, 256 * 4, stream);
    bn_stats_k<<<160, 128, 0, stream>>>(y, bn_sums, N);
    bn_scale_k<<<1, 128, 0, stream>>>(bn_sums, bn_gamma, bn_beta, bn_scale, bn_shift, N);

    // ---- normalize + global max pool
    pool_init_k<<<(N_GRAPHS * 128 + 255) / 256, 256, 0, stream>>>(pool_u);
    norm_pool_k<<<((size_t)N * 128 + 255) / 256, 256, 0, stream>>>(y, bn_scale, bn_shift, batch,
                                                                   pool_u, N);
    pool_write_k<<<(N_GRAPHS * 128 + 255) / 256, 256, 0, stream>>>(pool_u, out_pool);
}